// Round 7
// baseline (150.723 us; speedup 1.0000x reference)
//
#include <hip/hip_runtime.h>
#include <hip/hip_bf16.h>

// MHA fwd: B=2, S=2048, D=256, H=8, Dh=32.
// Outputs: out [2,2048,256] fp32, attn_mean [2,2048,2048] fp32 (concat in d_out).
//
// R6: arithmetic-intensity bump in the two S^2 kernels.
//  - attn_write: 32q x 256k per block (2 q-tiles share every K fragment load)
//    -> K L2 traffic halved (256->128MB), 2x chain ILP.
//  - attn_flash: 2 q-tiles per wave sharing K/V loads -> loads/iter unchanged,
//    mfma/exp per iter doubled (ILP x2), wave count 4096 (4/SIMD, enough per R3).
// Everything else unchanged from R5 (fragment-linear layouts everywhere).

#define B_   2
#define S_   2048
#define D_   256
#define H_   8
#define DH_  32
#define NROW (B_*S_)      // 4096
#define KSPLIT 4
#define KKEYS (S_/KSPLIT) // 512

typedef __attribute__((ext_vector_type(8))) short bf16x8;  // 8 bf16 (4 VGPRs)
typedef __attribute__((ext_vector_type(4))) float f32x4;

__device__ __forceinline__ f32x4 mfma_bf16(bf16x8 a, bf16x8 b, f32x4 c) {
    return __builtin_amdgcn_mfma_f32_16x16x32_bf16(a, b, c, 0, 0, 0);
}

__device__ __forceinline__ unsigned short f2bf_bits(float v) {
    __hip_bfloat16 h = __float2bfloat16(v);
    return *reinterpret_cast<unsigned short*>(&h);
}

// fragment-linear index for a row-major [R x 256] matrix element (m, k)
__device__ __forceinline__ size_t fragidx(int m, int k) {
    return (size_t)(m >> 4) * 4096 + (k >> 5) * 512 + ((k >> 3) & 3) * 128
           + (m & 15) * 8 + (k & 7);
}

// ---------------- split fp32 -> (hi, lo) bf16, fragment-linear, one launch ----------------
__global__ void split_all(const float4* __restrict__ x,
                          const float4* __restrict__ wq, const float4* __restrict__ wk,
                          const float4* __restrict__ wv, const float4* __restrict__ wc,
                          ushort4* __restrict__ xh, ushort4* __restrict__ xl,
                          ushort4* __restrict__ wqh, ushort4* __restrict__ wql,
                          ushort4* __restrict__ wkh, ushort4* __restrict__ wkl,
                          ushort4* __restrict__ wvh, ushort4* __restrict__ wvl,
                          ushort4* __restrict__ wch, ushort4* __restrict__ wcl) {
    int i = blockIdx.x * 256 + threadIdx.x;   // total 327680 float4s
    const float4* src; ushort4 *ph, *pl; int off;
    if (i < 262144) { src = x; ph = xh; pl = xl; off = i; }
    else {
        int j = i - 262144;
        int rg = j >> 14; off = j & 16383;
        if (rg == 0)      { src = wq; ph = wqh; pl = wql; }
        else if (rg == 1) { src = wk; ph = wkh; pl = wkl; }
        else if (rg == 2) { src = wv; ph = wvh; pl = wvl; }
        else              { src = wc; ph = wch; pl = wcl; }
    }
    float4 v = src[off];
    float vv[4] = {v.x, v.y, v.z, v.w};
    ushort4 hb, lb;
    unsigned short* hp = (unsigned short*)&hb;
    unsigned short* lp = (unsigned short*)&lb;
    for (int c = 0; c < 4; c++) {
        __hip_bfloat16 h = __float2bfloat16(vv[c]);
        hp[c] = *reinterpret_cast<unsigned short*>(&h);
        lp[c] = f2bf_bits(vv[c] - __bfloat162float(h));
    }
    int m = off >> 6, k = (off & 63) * 4;
    size_t fi = fragidx(m, k);          // divisible by 4
    ph[fi >> 2] = hb;
    pl[fi >> 2] = lb;
}

// ---------------- QKV projection: y = x @ W^T + b ----------------
// grid (NROW/64=64, 4, 3), block 256 (4 waves, 2x2 wave tiles of 32x32).
__global__ __launch_bounds__(256) void qkv_gemm(
    const __hip_bfloat16* __restrict__ xh, const __hip_bfloat16* __restrict__ xl,
    const __hip_bfloat16* __restrict__ w0h, const __hip_bfloat16* __restrict__ w0l,
    const __hip_bfloat16* __restrict__ w1h, const __hip_bfloat16* __restrict__ w1l,
    const __hip_bfloat16* __restrict__ w2h, const __hip_bfloat16* __restrict__ w2l,
    const float* __restrict__ bq, const float* __restrict__ bk, const float* __restrict__ bvv,
    __hip_bfloat16* __restrict__ Qf, __hip_bfloat16* __restrict__ Kf,
    __hip_bfloat16* __restrict__ Vf)
{
    int z = blockIdx.z;
    const __hip_bfloat16* wh = (z==0) ? w0h : (z==1) ? w1h : w2h;
    const __hip_bfloat16* wl = (z==0) ? w0l : (z==1) ? w1l : w2l;
    const float* bias = (z==0) ? bq : (z==1) ? bk : bvv;
    const float sv = (z==0) ? 0.17677669529663687f * 1.4426950408889634f : 1.0f;

    int tid = threadIdx.x;
    int w = tid >> 6, lid = tid & 63, quad = lid >> 4, l15 = lid & 15;
    int row0 = blockIdx.x * 64 + (w >> 1) * 32;
    int col0 = blockIdx.y * 64 + (w & 1) * 32;

    f32x4 acc[2][2] = {};
#pragma unroll
    for (int k0 = 0; k0 < 256; k0 += 32) {
        bf16x8 ah[2], al[2], bh[2], bl[2];
        for (int mi = 0; mi < 2; mi++) {
            size_t ro = (size_t)((row0 + mi * 16) >> 4) * 4096 + (k0 >> 5) * 512 + lid * 8;
            ah[mi] = *(const bf16x8*)(xh + ro);
            al[mi] = *(const bf16x8*)(xl + ro);
        }
        for (int ni = 0; ni < 2; ni++) {
            size_t co = (size_t)((col0 + ni * 16) >> 4) * 4096 + (k0 >> 5) * 512 + lid * 8;
            bh[ni] = *(const bf16x8*)(wh + co);
            bl[ni] = *(const bf16x8*)(wl + co);
        }
        for (int mi = 0; mi < 2; mi++)
            for (int ni = 0; ni < 2; ni++) {
                acc[mi][ni] = mfma_bf16(ah[mi], bh[ni], acc[mi][ni]);
                acc[mi][ni] = mfma_bf16(ah[mi], bl[ni], acc[mi][ni]);
                acc[mi][ni] = mfma_bf16(al[mi], bh[ni], acc[mi][ni]);
            }
    }
    for (int mi = 0; mi < 2; mi++)
        for (int ni = 0; ni < 2; ni++) {
            int col = col0 + ni * 16 + l15;       // D-layout: col = lane&15
            int h = col >> 5, dh = col & 31;
            float bvl = bias[col];
            for (int r = 0; r < 4; r++) {
                int row = row0 + mi * 16 + quad * 4 + r;  // D-layout: row = quad*4+r
                int b = row >> 11, s = row & 2047;
                __hip_bfloat16 o = __float2bfloat16((acc[mi][ni][r] + bvl) * sv);
                size_t bh_base = (size_t)(b * H_ + h) * (S_ * DH_);
                if (z == 2) {
                    int oo = s & 31;
                    int slot = ((oo & 15) >> 2) * 8 + ((oo >> 4) << 2) + (oo & 3);
                    Vf[bh_base + (s >> 5) * 1024 + (dh >> 4) * 512
                       + (slot >> 3) * 128 + (dh & 15) * 8 + (slot & 7)] = o;
                } else {
                    size_t idx = bh_base + (s >> 4) * 512 + (dh >> 3) * 128
                                 + (s & 15) * 8 + (dh & 7);
                    if (z == 0) Qf[idx] = o; else Kf[idx] = o;
                }
            }
        }
}

// ---------------- flash pass: partial l and O' ----------------
// grid (S/128=16, H=8, B*KSPLIT=8), block 256 = 4 waves.
// Each wave owns TWO q16-tiles sharing every K/V fragment load.
__global__ __launch_bounds__(256) void attn_flash(
    const __hip_bfloat16* __restrict__ Qf, const __hip_bfloat16* __restrict__ Kf,
    const __hip_bfloat16* __restrict__ Vf,
    float* __restrict__ Opart, float* __restrict__ Lpart)
{
    int tid = threadIdx.x, w = tid >> 6, lid = tid & 63, quad = lid >> 4, l15 = lid & 15;
    int h = blockIdx.y;
    int b = blockIdx.z >> 2, ks = blockIdx.z & 3;
    int q0 = (blockIdx.x * 8 + w * 2) * 16;     // tiles q0 and q0+16
    size_t bh_base = (size_t)(b * H_ + h) * (S_ * DH_);
    const __hip_bfloat16* Qp = Qf + bh_base + (q0 >> 4) * 512 + lid * 8;
    const __hip_bfloat16* Kp = Kf + bh_base + lid * 8;
    const __hip_bfloat16* Vp = Vf + bh_base + lid * 8;
    bf16x8 qfa = *(const bf16x8*)Qp;
    bf16x8 qfb = *(const bf16x8*)(Qp + 512);
    f32x4 zacc = {};
    f32x4 oacc[2][2] = {};
    float lpa = 0.f, lpb = 0.f;

#pragma unroll 2
    for (int k0 = ks * KKEYS; k0 < (ks + 1) * KKEYS; k0 += 32) {
        bf16x8 kf0 = *(const bf16x8*)(Kp + (k0 >> 4) * 512);
        bf16x8 kf1 = *(const bf16x8*)(Kp + (k0 >> 4) * 512 + 512);
        bf16x8 vf0 = *(const bf16x8*)(Vp + (k0 >> 5) * 1024);
        bf16x8 vf1 = *(const bf16x8*)(Vp + (k0 >> 5) * 1024 + 512);
        // S^T = K.Q^T for both q-tiles (shared kf)
        f32x4 ca0 = mfma_bf16(kf0, qfa, zacc);
        f32x4 ca1 = mfma_bf16(kf1, qfa, zacc);
        f32x4 cb0 = mfma_bf16(kf0, qfb, zacc);
        f32x4 cb1 = mfma_bf16(kf1, qfb, zacc);
        float ea0[4], ea1[4], eb0[4], eb1[4];
        for (int r = 0; r < 4; r++) {
            ea0[r] = exp2f(ca0[r]); ea1[r] = exp2f(ca1[r]);
            eb0[r] = exp2f(cb0[r]); eb1[r] = exp2f(cb1[r]);
        }
        lpa += ea0[0] + ea0[1] + ea0[2] + ea0[3] + ea1[0] + ea1[1] + ea1[2] + ea1[3];
        lpb += eb0[0] + eb0[1] + eb0[2] + eb0[3] + eb1[0] + eb1[1] + eb1[2] + eb1[3];
        union { bf16x8 v; __hip_bfloat162 h2[4]; } pa, pb;
        pa.h2[0] = __float22bfloat162_rn(make_float2(ea0[0], ea0[1]));
        pa.h2[1] = __float22bfloat162_rn(make_float2(ea0[2], ea0[3]));
        pa.h2[2] = __float22bfloat162_rn(make_float2(ea1[0], ea1[1]));
        pa.h2[3] = __float22bfloat162_rn(make_float2(ea1[2], ea1[3]));
        pb.h2[0] = __float22bfloat162_rn(make_float2(eb0[0], eb0[1]));
        pb.h2[1] = __float22bfloat162_rn(make_float2(eb0[2], eb0[3]));
        pb.h2[2] = __float22bfloat162_rn(make_float2(eb1[0], eb1[1]));
        pb.h2[3] = __float22bfloat162_rn(make_float2(eb1[2], eb1[3]));
        // O^T = V^T.P^T (shared vf)
        oacc[0][0] = mfma_bf16(vf0, pa.v, oacc[0][0]);
        oacc[0][1] = mfma_bf16(vf1, pa.v, oacc[0][1]);
        oacc[1][0] = mfma_bf16(vf0, pb.v, oacc[1][0]);
        oacc[1][1] = mfma_bf16(vf1, pb.v, oacc[1][1]);
    }
    lpa += __shfl_xor(lpa, 16); lpa += __shfl_xor(lpa, 32);
    lpb += __shfl_xor(lpb, 16); lpb += __shfl_xor(lpb, 32);

    size_t base = (size_t)((b * H_ + h) * KSPLIT + ks) * S_;
    if (lid < 16) {
        Lpart[base + q0 + lid] = lpa;
        Lpart[base + q0 + 16 + lid] = lpb;
    }
    f32x4* opa = (f32x4*)(Opart + (base + q0 + l15) * DH_);
    opa[quad] = oacc[0][0];
    opa[quad + 4] = oacc[0][1];
    f32x4* opb = (f32x4*)(Opart + (base + q0 + 16 + l15) * DH_);
    opb[quad] = oacc[1][0];
    opb[quad + 4] = oacc[1][1];
}

// ---------------- combine: ctx = sum(O')/sum(l) -> fragment-linear hi/lo, invL ----------------
__global__ __launch_bounds__(256) void attn_combine(
    const float* __restrict__ Opart, const float* __restrict__ Lpart,
    __hip_bfloat16* __restrict__ cth, __hip_bfloat16* __restrict__ ctl,
    float* __restrict__ invL)
{
    int i = blockIdx.x * 256 + threadIdx.x;   // B*H*S*DH = 1,048,576
    int dh = i & 31;
    int s = (i >> 5) & (S_ - 1);
    int hb = i >> 16;                          // b*H+h in [0,16)
    float l = 0.f, o = 0.f;
#pragma unroll
    for (int ks = 0; ks < KSPLIT; ks++) {
        size_t base = (size_t)(hb * KSPLIT + ks) * S_ + s;
        l += Lpart[base];
        o += Opart[base * DH_ + dh];
    }
    float inv = 1.0f / l;
    float val = o * inv;
    int b = hb >> 3, h = hb & 7;
    size_t fi = fragidx(b * S_ + s, h * DH_ + dh);
    __hip_bfloat16 hv = __float2bfloat16(val);
    cth[fi] = hv;
    ctl[fi] = __float2bfloat16(val - __bfloat162float(hv));
    if (dh == 0) invL[hb * S_ + s] = inv;
}

// ---------------- attn write: head-mean probs, 32q x 256k per block ----------------
// grid (S/256=8, S/32=64, B=2) = 1024 blocks; wave w owns cols k0+w*64..+64.
// 2 q-tiles share every K fragment load.
__global__ __launch_bounds__(256) void attn_write(
    const __hip_bfloat16* __restrict__ Qf, const __hip_bfloat16* __restrict__ Kf,
    const float* __restrict__ invL, float* __restrict__ attn)
{
    __shared__ float invbuf[H_ * 32];
    int tid = threadIdx.x, w = tid >> 6, lid = tid & 63, quad = lid >> 4, l15 = lid & 15;
    int b = blockIdx.z;
    int q0 = blockIdx.y * 32;
    int k0 = blockIdx.x * 256 + w * 64;
    {
        int h = tid >> 5, r = tid & 31;  // 256 threads cover 8 heads x 32 q
        invbuf[tid] = invL[(b * H_ + h) * S_ + q0 + r] * 0.125f;  // fold 1/H
    }
    __syncthreads();
    f32x4 zacc = {};
    float psum[2][4][4] = {};
    for (int h = 0; h < H_; h++) {
        size_t bh_base = (size_t)(b * H_ + h) * (S_ * DH_);
        bf16x8 qf0 = *(const bf16x8*)(Qf + bh_base + (q0 >> 4) * 512 + lid * 8);
        bf16x8 qf1 = *(const bf16x8*)(Qf + bh_base + (q0 >> 4) * 512 + 512 + lid * 8);
        const __hip_bfloat16* Kp = Kf + bh_base + (k0 >> 4) * 512 + lid * 8;
        float il0[4], il1[4];
        for (int r = 0; r < 4; r++) {
            il0[r] = invbuf[h * 32 + quad * 4 + r];
            il1[r] = invbuf[h * 32 + 16 + quad * 4 + r];
        }
        for (int nt = 0; nt < 4; nt++) {
            bf16x8 kf = *(const bf16x8*)(Kp + nt * 512);
            f32x4 c0 = mfma_bf16(qf0, kf, zacc);  // C: row=q (quad*4+r), col=key (l15)
            f32x4 c1 = mfma_bf16(qf1, kf, zacc);
            for (int r = 0; r < 4; r++) {
                psum[0][nt][r] += exp2f(c0[r]) * il0[r];
                psum[1][nt][r] += exp2f(c1[r]) * il1[r];
            }
        }
    }
    for (int qt = 0; qt < 2; qt++)
        for (int nt = 0; nt < 4; nt++)
            for (int r = 0; r < 4; r++)
                attn[(size_t)(b * S_ + q0 + qt * 16 + quad * 4 + r) * S_
                     + k0 + nt * 16 + l15] = psum[qt][nt][r];
}

// ---------------- output projection: out = ctx @ wc^T + bc (fp32 out) ----------------
// grid (NROW/64=64, 4), block 256 (4 waves, 2x2 wave tiles of 32x32).
__global__ __launch_bounds__(256) void out_gemm(
    const __hip_bfloat16* __restrict__ ch, const __hip_bfloat16* __restrict__ cl,
    const __hip_bfloat16* __restrict__ wh, const __hip_bfloat16* __restrict__ wl,
    const float* __restrict__ bias, float* __restrict__ out)
{
    int tid = threadIdx.x;
    int w = tid >> 6, lid = tid & 63, quad = lid >> 4, l15 = lid & 15;
    int row0 = blockIdx.x * 64 + (w >> 1) * 32;
    int col0 = blockIdx.y * 64 + (w & 1) * 32;

    f32x4 acc[2][2] = {};
#pragma unroll
    for (int k0 = 0; k0 < 256; k0 += 32) {
        bf16x8 ah[2], al[2], bh[2], bl[2];
        for (int mi = 0; mi < 2; mi++) {
            size_t ro = (size_t)((row0 + mi * 16) >> 4) * 4096 + (k0 >> 5) * 512 + lid * 8;
            ah[mi] = *(const bf16x8*)(ch + ro);
            al[mi] = *(const bf16x8*)(cl + ro);
        }
        for (int ni = 0; ni < 2; ni++) {
            size_t co = (size_t)((col0 + ni * 16) >> 4) * 4096 + (k0 >> 5) * 512 + lid * 8;
            bh[ni] = *(const bf16x8*)(wh + co);
            bl[ni] = *(const bf16x8*)(wl + co);
        }
        for (int mi = 0; mi < 2; mi++)
            for (int ni = 0; ni < 2; ni++) {
                acc[mi][ni] = mfma_bf16(ah[mi], bh[ni], acc[mi][ni]);
                acc[mi][ni] = mfma_bf16(ah[mi], bl[ni], acc[mi][ni]);
                acc[mi][ni] = mfma_bf16(al[mi], bh[ni], acc[mi][ni]);
            }
    }
    for (int mi = 0; mi < 2; mi++)
        for (int ni = 0; ni < 2; ni++) {
            int col = col0 + ni * 16 + l15;
            float bvl = bias[col];
            for (int r = 0; r < 4; r++) {
                int row = row0 + mi * 16 + quad * 4 + r;
                out[(size_t)row * 256 + col] = acc[mi][ni][r] + bvl;
            }
        }
}

extern "C" void kernel_launch(void* const* d_in, const int* in_sizes, int n_in,
                              void* d_out, int out_size, void* d_ws, size_t ws_size,
                              hipStream_t stream) {
    const float* x  = (const float*)d_in[0];
    const float* wq = (const float*)d_in[1];
    const float* bq = (const float*)d_in[2];
    const float* wk = (const float*)d_in[3];
    const float* bk = (const float*)d_in[4];
    const float* wv = (const float*)d_in[5];
    const float* bv = (const float*)d_in[6];
    const float* wc = (const float*)d_in[7];
    const float* bc = (const float*)d_in[8];

    char* ws = (char*)d_ws;
    const size_t MB = 1u << 20;
    const size_t KB128 = 128u * 1024u;
    __hip_bfloat16* xh  = (__hip_bfloat16*)(ws + 0 * MB);
    __hip_bfloat16* xl  = (__hip_bfloat16*)(ws + 2 * MB);
    __hip_bfloat16* wqh = (__hip_bfloat16*)(ws + 4 * MB + 0 * KB128);
    __hip_bfloat16* wql = (__hip_bfloat16*)(ws + 4 * MB + 1 * KB128);
    __hip_bfloat16* wkh = (__hip_bfloat16*)(ws + 4 * MB + 2 * KB128);
    __hip_bfloat16* wkl = (__hip_bfloat16*)(ws + 4 * MB + 3 * KB128);
    __hip_bfloat16* wvh = (__hip_bfloat16*)(ws + 4 * MB + 4 * KB128);
    __hip_bfloat16* wvl = (__hip_bfloat16*)(ws + 4 * MB + 5 * KB128);
    __hip_bfloat16* wch = (__hip_bfloat16*)(ws + 4 * MB + 6 * KB128);
    __hip_bfloat16* wcl = (__hip_bfloat16*)(ws + 4 * MB + 7 * KB128);
    __hip_bfloat16* Qfb = (__hip_bfloat16*)(ws + 5 * MB);
    __hip_bfloat16* Kfb = (__hip_bfloat16*)(ws + 7 * MB);
    __hip_bfloat16* Vfb = (__hip_bfloat16*)(ws + 9 * MB);
    __hip_bfloat16* cth = (__hip_bfloat16*)(ws + 11 * MB);
    __hip_bfloat16* ctl = (__hip_bfloat16*)(ws + 13 * MB);
    float* Opart = (float*)(ws + 15 * MB);                    // 16 MB (KSPLIT=4)
    float* Lpart = (float*)(ws + 31 * MB);                    // 512 KB
    float* invL  = (float*)(ws + 31 * MB + 512 * 1024);       // 128 KB

    float* outp  = (float*)d_out;
    float* attnp = outp + (size_t)NROW * D_;  // outputs concatenated: out, attention

    hipLaunchKernelGGL(split_all, dim3(1280), dim3(256), 0, stream,
                       (const float4*)x, (const float4*)wq, (const float4*)wk,
                       (const float4*)wv, (const float4*)wc,
                       (ushort4*)xh, (ushort4*)xl,
                       (ushort4*)wqh, (ushort4*)wql, (ushort4*)wkh, (ushort4*)wkl,
                       (ushort4*)wvh, (ushort4*)wvl, (ushort4*)wch, (ushort4*)wcl);

    hipLaunchKernelGGL(qkv_gemm, dim3(NROW / 64, 4, 3), dim3(256), 0, stream,
                       xh, xl, wqh, wql, wkh, wkl, wvh, wvl, bq, bk, bv, Qfb, Kfb, Vfb);

    hipLaunchKernelGGL(attn_flash, dim3(S_ / 128, H_, B_ * KSPLIT), dim3(256), 0, stream,
                       Qfb, Kfb, Vfb, Opart, Lpart);

    hipLaunchKernelGGL(attn_combine, dim3(4096), dim3(256), 0, stream,
                       Opart, Lpart, cth, ctl, invL);

    hipLaunchKernelGGL(attn_write, dim3(S_ / 256, S_ / 32, B_), dim3(256), 0, stream,
                       Qfb, Kfb, invL, attnp);

    hipLaunchKernelGGL(out_gemm, dim3(NROW / 64, 4), dim3(256), 0, stream,
                       cth, ctl, wch, wcl, bc, outp);
}

// Round 8
// 141.747 us; speedup vs baseline: 1.0633x; 1.0633x over previous
//
#include <hip/hip_runtime.h>
#include <hip/hip_bf16.h>

// MHA fwd: B=2, S=2048, D=256, H=8, Dh=32.
// Outputs: out [2,2048,256] fp32, attn_mean [2,2048,2048] fp32 (concat in d_out).
//
// R7: R5 shapes (R6's AI-bump was neutral->reverted) + native exp.
// exp2f lowers to OCML precise exp2 (~10 VALU ops, denormal-correct);
// __builtin_amdgcn_exp2f is raw v_exp_f32 (1 op, quarter-rate). 134M exps
// across attn_flash+attn_write make this a ~4x VALU cut in the S^2 loops.
// (R2 evidence: __expf->exp2f raised VALUBusy 24->35% at equal duration.)

#define B_   2
#define S_   2048
#define D_   256
#define H_   8
#define DH_  32
#define NROW (B_*S_)      // 4096
#define KSPLIT 4
#define KKEYS (S_/KSPLIT) // 512

typedef __attribute__((ext_vector_type(8))) short bf16x8;  // 8 bf16 (4 VGPRs)
typedef __attribute__((ext_vector_type(4))) float f32x4;

__device__ __forceinline__ f32x4 mfma_bf16(bf16x8 a, bf16x8 b, f32x4 c) {
    return __builtin_amdgcn_mfma_f32_16x16x32_bf16(a, b, c, 0, 0, 0);
}

__device__ __forceinline__ float fast_exp2(float x) {
    return __builtin_amdgcn_exp2f(x);   // v_exp_f32
}

__device__ __forceinline__ unsigned short f2bf_bits(float v) {
    __hip_bfloat16 h = __float2bfloat16(v);
    return *reinterpret_cast<unsigned short*>(&h);
}

// fragment-linear index for a row-major [R x 256] matrix element (m, k)
__device__ __forceinline__ size_t fragidx(int m, int k) {
    return (size_t)(m >> 4) * 4096 + (k >> 5) * 512 + ((k >> 3) & 3) * 128
           + (m & 15) * 8 + (k & 7);
}

// ---------------- split fp32 -> (hi, lo) bf16, fragment-linear, one launch ----------------
__global__ void split_all(const float4* __restrict__ x,
                          const float4* __restrict__ wq, const float4* __restrict__ wk,
                          const float4* __restrict__ wv, const float4* __restrict__ wc,
                          ushort4* __restrict__ xh, ushort4* __restrict__ xl,
                          ushort4* __restrict__ wqh, ushort4* __restrict__ wql,
                          ushort4* __restrict__ wkh, ushort4* __restrict__ wkl,
                          ushort4* __restrict__ wvh, ushort4* __restrict__ wvl,
                          ushort4* __restrict__ wch, ushort4* __restrict__ wcl) {
    int i = blockIdx.x * 256 + threadIdx.x;   // total 327680 float4s
    const float4* src; ushort4 *ph, *pl; int off;
    if (i < 262144) { src = x; ph = xh; pl = xl; off = i; }
    else {
        int j = i - 262144;
        int rg = j >> 14; off = j & 16383;
        if (rg == 0)      { src = wq; ph = wqh; pl = wql; }
        else if (rg == 1) { src = wk; ph = wkh; pl = wkl; }
        else if (rg == 2) { src = wv; ph = wvh; pl = wvl; }
        else              { src = wc; ph = wch; pl = wcl; }
    }
    float4 v = src[off];
    float vv[4] = {v.x, v.y, v.z, v.w};
    ushort4 hb, lb;
    unsigned short* hp = (unsigned short*)&hb;
    unsigned short* lp = (unsigned short*)&lb;
    for (int c = 0; c < 4; c++) {
        __hip_bfloat16 h = __float2bfloat16(vv[c]);
        hp[c] = *reinterpret_cast<unsigned short*>(&h);
        lp[c] = f2bf_bits(vv[c] - __bfloat162float(h));
    }
    int m = off >> 6, k = (off & 63) * 4;
    size_t fi = fragidx(m, k);          // divisible by 4
    ph[fi >> 2] = hb;
    pl[fi >> 2] = lb;
}

// ---------------- QKV projection: y = x @ W^T + b ----------------
// grid (NROW/64=64, 4, 3), block 256 (4 waves, 2x2 wave tiles of 32x32).
__global__ __launch_bounds__(256) void qkv_gemm(
    const __hip_bfloat16* __restrict__ xh, const __hip_bfloat16* __restrict__ xl,
    const __hip_bfloat16* __restrict__ w0h, const __hip_bfloat16* __restrict__ w0l,
    const __hip_bfloat16* __restrict__ w1h, const __hip_bfloat16* __restrict__ w1l,
    const __hip_bfloat16* __restrict__ w2h, const __hip_bfloat16* __restrict__ w2l,
    const float* __restrict__ bq, const float* __restrict__ bk, const float* __restrict__ bvv,
    __hip_bfloat16* __restrict__ Qf, __hip_bfloat16* __restrict__ Kf,
    __hip_bfloat16* __restrict__ Vf)
{
    int z = blockIdx.z;
    const __hip_bfloat16* wh = (z==0) ? w0h : (z==1) ? w1h : w2h;
    const __hip_bfloat16* wl = (z==0) ? w0l : (z==1) ? w1l : w2l;
    const float* bias = (z==0) ? bq : (z==1) ? bk : bvv;
    const float sv = (z==0) ? 0.17677669529663687f * 1.4426950408889634f : 1.0f;

    int tid = threadIdx.x;
    int w = tid >> 6, lid = tid & 63, quad = lid >> 4, l15 = lid & 15;
    int row0 = blockIdx.x * 64 + (w >> 1) * 32;
    int col0 = blockIdx.y * 64 + (w & 1) * 32;

    f32x4 acc[2][2] = {};
#pragma unroll
    for (int k0 = 0; k0 < 256; k0 += 32) {
        bf16x8 ah[2], al[2], bh[2], bl[2];
        for (int mi = 0; mi < 2; mi++) {
            size_t ro = (size_t)((row0 + mi * 16) >> 4) * 4096 + (k0 >> 5) * 512 + lid * 8;
            ah[mi] = *(const bf16x8*)(xh + ro);
            al[mi] = *(const bf16x8*)(xl + ro);
        }
        for (int ni = 0; ni < 2; ni++) {
            size_t co = (size_t)((col0 + ni * 16) >> 4) * 4096 + (k0 >> 5) * 512 + lid * 8;
            bh[ni] = *(const bf16x8*)(wh + co);
            bl[ni] = *(const bf16x8*)(wl + co);
        }
        for (int mi = 0; mi < 2; mi++)
            for (int ni = 0; ni < 2; ni++) {
                acc[mi][ni] = mfma_bf16(ah[mi], bh[ni], acc[mi][ni]);
                acc[mi][ni] = mfma_bf16(ah[mi], bl[ni], acc[mi][ni]);
                acc[mi][ni] = mfma_bf16(al[mi], bh[ni], acc[mi][ni]);
            }
    }
    for (int mi = 0; mi < 2; mi++)
        for (int ni = 0; ni < 2; ni++) {
            int col = col0 + ni * 16 + l15;       // D-layout: col = lane&15
            int h = col >> 5, dh = col & 31;
            float bvl = bias[col];
            for (int r = 0; r < 4; r++) {
                int row = row0 + mi * 16 + quad * 4 + r;  // D-layout: row = quad*4+r
                int b = row >> 11, s = row & 2047;
                __hip_bfloat16 o = __float2bfloat16((acc[mi][ni][r] + bvl) * sv);
                size_t bh_base = (size_t)(b * H_ + h) * (S_ * DH_);
                if (z == 2) {
                    int oo = s & 31;
                    int slot = ((oo & 15) >> 2) * 8 + ((oo >> 4) << 2) + (oo & 3);
                    Vf[bh_base + (s >> 5) * 1024 + (dh >> 4) * 512
                       + (slot >> 3) * 128 + (dh & 15) * 8 + (slot & 7)] = o;
                } else {
                    size_t idx = bh_base + (s >> 4) * 512 + (dh >> 3) * 128
                                 + (s & 15) * 8 + (dh & 7);
                    if (z == 0) Qf[idx] = o; else Kf[idx] = o;
                }
            }
        }
}

// ---------------- flash pass: partial l and O' per (b,h,q16,ksplit) ----------------
// grid (S/64=32, H=8, B*KSPLIT=8), block 256 = 4 waves, one q16-tile per wave.
__global__ __launch_bounds__(256) void attn_flash(
    const __hip_bfloat16* __restrict__ Qf, const __hip_bfloat16* __restrict__ Kf,
    const __hip_bfloat16* __restrict__ Vf,
    float* __restrict__ Opart, float* __restrict__ Lpart)
{
    int tid = threadIdx.x, w = tid >> 6, lid = tid & 63, quad = lid >> 4, l15 = lid & 15;
    int h = blockIdx.y;
    int b = blockIdx.z >> 2, ks = blockIdx.z & 3;
    int q0 = (blockIdx.x * 4 + w) * 16;
    size_t bh_base = (size_t)(b * H_ + h) * (S_ * DH_);
    const __hip_bfloat16* Qp = Qf + bh_base + (q0 >> 4) * 512 + lid * 8;
    const __hip_bfloat16* Kp = Kf + bh_base + lid * 8;
    const __hip_bfloat16* Vp = Vf + bh_base + lid * 8;
    bf16x8 qf = *(const bf16x8*)Qp;                 // B: n=q (lane&15), k=dh
    f32x4 zacc = {};
    f32x4 oacc[2] = {};
    float lp0 = 0.f, lp1 = 0.f;

#pragma unroll 2
    for (int k0 = ks * KKEYS; k0 < (ks + 1) * KKEYS; k0 += 32) {
        bf16x8 kf0 = *(const bf16x8*)(Kp + (k0 >> 4) * 512);
        bf16x8 kf1 = *(const bf16x8*)(Kp + (k0 >> 4) * 512 + 512);
        f32x4 c0 = mfma_bf16(kf0, qf, zacc);   // keys k0+quad*4+r, q=l15
        f32x4 c1 = mfma_bf16(kf1, qf, zacc);   // keys k0+16+quad*4+r
        float e0[4], e1[4];
        for (int r = 0; r < 4; r++) {
            e0[r] = fast_exp2(c0[r]);
            e1[r] = fast_exp2(c1[r]);
        }
        lp0 += e0[0] + e0[1] + e0[2] + e0[3];
        lp1 += e1[0] + e1[1] + e1[2] + e1[3];
        union { bf16x8 v; __hip_bfloat162 h2[4]; } pu;
        pu.h2[0] = __float22bfloat162_rn(make_float2(e0[0], e0[1]));
        pu.h2[1] = __float22bfloat162_rn(make_float2(e0[2], e0[3]));
        pu.h2[2] = __float22bfloat162_rn(make_float2(e1[0], e1[1]));
        pu.h2[3] = __float22bfloat162_rn(make_float2(e1[2], e1[3]));
        bf16x8 vf0 = *(const bf16x8*)(Vp + (k0 >> 5) * 1024);
        bf16x8 vf1 = *(const bf16x8*)(Vp + (k0 >> 5) * 1024 + 512);
        oacc[0] = mfma_bf16(vf0, pu.v, oacc[0]);   // d 0..15
        oacc[1] = mfma_bf16(vf1, pu.v, oacc[1]);   // d 16..31
    }
    float lp = lp0 + lp1;
    lp += __shfl_xor(lp, 16);
    lp += __shfl_xor(lp, 32);

    size_t base = (size_t)((b * H_ + h) * KSPLIT + ks) * S_;
    if (lid < 16) Lpart[base + q0 + lid] = lp;
    f32x4* op = (f32x4*)(Opart + (base + q0 + l15) * DH_);
    op[quad] = oacc[0];
    op[quad + 4] = oacc[1];
}

// ---------------- combine: ctx = sum(O')/sum(l) -> fragment-linear hi/lo, invL ----------------
__global__ __launch_bounds__(256) void attn_combine(
    const float* __restrict__ Opart, const float* __restrict__ Lpart,
    __hip_bfloat16* __restrict__ cth, __hip_bfloat16* __restrict__ ctl,
    float* __restrict__ invL)
{
    int i = blockIdx.x * 256 + threadIdx.x;   // B*H*S*DH = 1,048,576
    int dh = i & 31;
    int s = (i >> 5) & (S_ - 1);
    int hb = i >> 16;                          // b*H+h in [0,16)
    float l = 0.f, o = 0.f;
#pragma unroll
    for (int ks = 0; ks < KSPLIT; ks++) {
        size_t base = (size_t)(hb * KSPLIT + ks) * S_ + s;
        l += Lpart[base];
        o += Opart[base * DH_ + dh];
    }
    float inv = 1.0f / l;
    float val = o * inv;
    int b = hb >> 3, h = hb & 7;
    size_t fi = fragidx(b * S_ + s, h * DH_ + dh);
    __hip_bfloat16 hv = __float2bfloat16(val);
    cth[fi] = hv;
    ctl[fi] = __float2bfloat16(val - __bfloat162float(hv));
    if (dh == 0) invL[hb * S_ + s] = inv;
}

// ---------------- attn write: head-mean probs, 16q x 256k per block ----------------
// grid (S/256=8, S/16=128, B=2) = 2048 blocks; wave w owns cols k0+w*64..+64.
__global__ __launch_bounds__(256) void attn_write(
    const __hip_bfloat16* __restrict__ Qf, const __hip_bfloat16* __restrict__ Kf,
    const float* __restrict__ invL, float* __restrict__ attn)
{
    __shared__ float invbuf[H_ * 16];
    int tid = threadIdx.x, w = tid >> 6, lid = tid & 63, quad = lid >> 4, l15 = lid & 15;
    int b = blockIdx.z;
    int q0 = blockIdx.y * 16;
    int k0 = blockIdx.x * 256 + w * 64;
    if (tid < 128) {
        int h = tid >> 4, r = tid & 15;
        invbuf[tid] = invL[(b * H_ + h) * S_ + q0 + r] * 0.125f;  // fold 1/H
    }
    __syncthreads();
    f32x4 zacc = {};
    float psum[4][4] = {};
    for (int h = 0; h < H_; h++) {
        size_t bh_base = (size_t)(b * H_ + h) * (S_ * DH_);
        bf16x8 qf = *(const bf16x8*)(Qf + bh_base + (q0 >> 4) * 512 + lid * 8);
        const __hip_bfloat16* Kp = Kf + bh_base + (k0 >> 4) * 512 + lid * 8;
        float il[4];
        for (int r = 0; r < 4; r++) il[r] = invbuf[h * 16 + quad * 4 + r];
        for (int nt = 0; nt < 4; nt++) {
            bf16x8 kf = *(const bf16x8*)(Kp + nt * 512);
            f32x4 c = mfma_bf16(qf, kf, zacc);  // C: row=q (quad*4+r), col=key (l15)
            for (int r = 0; r < 4; r++)
                psum[nt][r] += fast_exp2(c[r]) * il[r];
        }
    }
    for (int nt = 0; nt < 4; nt++)
        for (int r = 0; r < 4; r++)
            attn[(size_t)(b * S_ + q0 + quad * 4 + r) * S_ + k0 + nt * 16 + l15] =
                psum[nt][r];
}

// ---------------- output projection: out = ctx @ wc^T + bc (fp32 out) ----------------
// grid (NROW/64=64, 4), block 256 (4 waves, 2x2 wave tiles of 32x32).
__global__ __launch_bounds__(256) void out_gemm(
    const __hip_bfloat16* __restrict__ ch, const __hip_bfloat16* __restrict__ cl,
    const __hip_bfloat16* __restrict__ wh, const __hip_bfloat16* __restrict__ wl,
    const float* __restrict__ bias, float* __restrict__ out)
{
    int tid = threadIdx.x;
    int w = tid >> 6, lid = tid & 63, quad = lid >> 4, l15 = lid & 15;
    int row0 = blockIdx.x * 64 + (w >> 1) * 32;
    int col0 = blockIdx.y * 64 + (w & 1) * 32;

    f32x4 acc[2][2] = {};
#pragma unroll
    for (int k0 = 0; k0 < 256; k0 += 32) {
        bf16x8 ah[2], al[2], bh[2], bl[2];
        for (int mi = 0; mi < 2; mi++) {
            size_t ro = (size_t)((row0 + mi * 16) >> 4) * 4096 + (k0 >> 5) * 512 + lid * 8;
            ah[mi] = *(const bf16x8*)(ch + ro);
            al[mi] = *(const bf16x8*)(cl + ro);
        }
        for (int ni = 0; ni < 2; ni++) {
            size_t co = (size_t)((col0 + ni * 16) >> 4) * 4096 + (k0 >> 5) * 512 + lid * 8;
            bh[ni] = *(const bf16x8*)(wh + co);
            bl[ni] = *(const bf16x8*)(wl + co);
        }
        for (int mi = 0; mi < 2; mi++)
            for (int ni = 0; ni < 2; ni++) {
                acc[mi][ni] = mfma_bf16(ah[mi], bh[ni], acc[mi][ni]);
                acc[mi][ni] = mfma_bf16(ah[mi], bl[ni], acc[mi][ni]);
                acc[mi][ni] = mfma_bf16(al[mi], bh[ni], acc[mi][ni]);
            }
    }
    for (int mi = 0; mi < 2; mi++)
        for (int ni = 0; ni < 2; ni++) {
            int col = col0 + ni * 16 + l15;
            float bvl = bias[col];
            for (int r = 0; r < 4; r++) {
                int row = row0 + mi * 16 + quad * 4 + r;
                out[(size_t)row * 256 + col] = acc[mi][ni][r] + bvl;
            }
        }
}

extern "C" void kernel_launch(void* const* d_in, const int* in_sizes, int n_in,
                              void* d_out, int out_size, void* d_ws, size_t ws_size,
                              hipStream_t stream) {
    const float* x  = (const float*)d_in[0];
    const float* wq = (const float*)d_in[1];
    const float* bq = (const float*)d_in[2];
    const float* wk = (const float*)d_in[3];
    const float* bk = (const float*)d_in[4];
    const float* wv = (const float*)d_in[5];
    const float* bv = (const float*)d_in[6];
    const float* wc = (const float*)d_in[7];
    const float* bc = (const float*)d_in[8];

    char* ws = (char*)d_ws;
    const size_t MB = 1u << 20;
    const size_t KB128 = 128u * 1024u;
    __hip_bfloat16* xh  = (__hip_bfloat16*)(ws + 0 * MB);
    __hip_bfloat16* xl  = (__hip_bfloat16*)(ws + 2 * MB);
    __hip_bfloat16* wqh = (__hip_bfloat16*)(ws + 4 * MB + 0 * KB128);
    __hip_bfloat16* wql = (__hip_bfloat16*)(ws + 4 * MB + 1 * KB128);
    __hip_bfloat16* wkh = (__hip_bfloat16*)(ws + 4 * MB + 2 * KB128);
    __hip_bfloat16* wkl = (__hip_bfloat16*)(ws + 4 * MB + 3 * KB128);
    __hip_bfloat16* wvh = (__hip_bfloat16*)(ws + 4 * MB + 4 * KB128);
    __hip_bfloat16* wvl = (__hip_bfloat16*)(ws + 4 * MB + 5 * KB128);
    __hip_bfloat16* wch = (__hip_bfloat16*)(ws + 4 * MB + 6 * KB128);
    __hip_bfloat16* wcl = (__hip_bfloat16*)(ws + 4 * MB + 7 * KB128);
    __hip_bfloat16* Qfb = (__hip_bfloat16*)(ws + 5 * MB);
    __hip_bfloat16* Kfb = (__hip_bfloat16*)(ws + 7 * MB);
    __hip_bfloat16* Vfb = (__hip_bfloat16*)(ws + 9 * MB);
    __hip_bfloat16* cth = (__hip_bfloat16*)(ws + 11 * MB);
    __hip_bfloat16* ctl = (__hip_bfloat16*)(ws + 13 * MB);
    float* Opart = (float*)(ws + 15 * MB);                    // 16 MB (KSPLIT=4)
    float* Lpart = (float*)(ws + 31 * MB);                    // 512 KB
    float* invL  = (float*)(ws + 31 * MB + 512 * 1024);       // 128 KB

    float* outp  = (float*)d_out;
    float* attnp = outp + (size_t)NROW * D_;  // outputs concatenated: out, attention

    hipLaunchKernelGGL(split_all, dim3(1280), dim3(256), 0, stream,
                       (const float4*)x, (const float4*)wq, (const float4*)wk,
                       (const float4*)wv, (const float4*)wc,
                       (ushort4*)xh, (ushort4*)xl,
                       (ushort4*)wqh, (ushort4*)wql, (ushort4*)wkh, (ushort4*)wkl,
                       (ushort4*)wvh, (ushort4*)wvl, (ushort4*)wch, (ushort4*)wcl);

    hipLaunchKernelGGL(qkv_gemm, dim3(NROW / 64, 4, 3), dim3(256), 0, stream,
                       xh, xl, wqh, wql, wkh, wkl, wvh, wvl, bq, bk, bv, Qfb, Kfb, Vfb);

    hipLaunchKernelGGL(attn_flash, dim3(S_ / 64, H_, B_ * KSPLIT), dim3(256), 0, stream,
                       Qfb, Kfb, Vfb, Opart, Lpart);

    hipLaunchKernelGGL(attn_combine, dim3(4096), dim3(256), 0, stream,
                       Opart, Lpart, cth, ctl, invL);

    hipLaunchKernelGGL(attn_write, dim3(S_ / 256, S_ / 16, B_), dim3(256), 0, stream,
                       Qfb, Kfb, invL, attnp);

    hipLaunchKernelGGL(out_gemm, dim3(NROW / 64, 4), dim3(256), 0, stream,
                       cth, ctl, wch, wcl, bc, outp);
}